// Round 4
// baseline (152.589 us; speedup 1.0000x reference)
//
#include <hip/hip_runtime.h>
#include <stdint.h>

// Problem constants
#define B_   32
#define S_   512
#define D_   1024
#define H_   16
#define HD_  64
#define KD_  64
#define NH_  1024   // H*HD

typedef __attribute__((ext_vector_type(8))) short short8;
typedef __attribute__((ext_vector_type(4))) float floatx4;

#define GAS __attribute__((address_space(1)))
#define LAS __attribute__((address_space(3)))

__device__ __forceinline__ ushort f2bf(float f) {
  uint32_t u = __float_as_uint(f);
  u = u + 0x7FFFu + ((u >> 16) & 1u);   // round-to-nearest-even
  return (ushort)(u >> 16);
}

__device__ __forceinline__ float bf2f(ushort h) {
  return __uint_as_float(((uint32_t)h) << 16);
}

__device__ __forceinline__ void gload_lds16(const void* g, void* l) {
  // width=16 global->LDS DMA; LDS dest is wave-uniform base + lane*16
  __builtin_amdgcn_global_load_lds((const GAS uint32_t*)g, (LAS uint32_t*)l, 16, 0, 0);
}

#define BARRIER() asm volatile("s_barrier" ::: "memory")
#define WAITLGKM() asm volatile("s_waitcnt lgkmcnt(0)" ::: "memory")

// ---- split-convert the two downsample mats to hi/lo bf16: [2][64][512] ---
__global__ __launch_bounds__(256) void cvt_split(const float* __restrict__ kdm,
                                                 const float* __restrict__ vdm,
                                                 ushort* __restrict__ hi,
                                                 ushort* __restrict__ lo) {
  int i = blockIdx.x * 256 + threadIdx.x;        // 16384 float4s total
  const float* src = (i < 8192) ? kdm : vdm;
  int j = i & 8191;
  float4 v = ((const float4*)src)[j];
  ushort4 h, l;
  h.x = f2bf(v.x); l.x = f2bf(v.x - bf2f(h.x));
  h.y = f2bf(v.y); l.y = f2bf(v.y - bf2f(h.y));
  h.z = f2bf(v.z); l.z = f2bf(v.z - bf2f(h.z));
  h.w = f2bf(v.w); l.w = f2bf(v.w - bf2f(h.w));
  ((ushort4*)hi)[i] = h;
  ((ushort4*)lo)[i] = l;
}

// ---- R14: pre_kv = {downsample(512) | transpose kkT/vkT(2048)} ----------
__global__ __launch_bounds__(256, 6) void pre_kv(
    const float* __restrict__ key, const float* __restrict__ value,
    const float* __restrict__ kkm, const float* __restrict__ vkm,
    const ushort* __restrict__ dsm_hi, const ushort* __restrict__ dsm_lo,
    ushort* __restrict__ kkT, ushort* __restrict__ vkT,
    ushort* __restrict__ outk, ushort* __restrict__ outv) {
  __shared__ __align__(16) char smem[26624];
  const int blk = blockIdx.x;
  const int tid = threadIdx.x;

  if (blk < 512) {
    // ================= downsample (32-wide s-chunks) ======================
    const int bz = (blk & 7) + ((blk >> 6) << 3);
    const int t  = (blk >> 3) & 7;
    const int z = bz >> 5, b = bz & 31;
    const int c0 = t * 128;
    const float* in = z ? value : key;
    ushort* out     = z ? outv : outk;
    const ushort* Ah = dsm_hi + (size_t)z * (KD_ * S_);
    const ushort* Al = dsm_lo + (size_t)z * (KD_ * S_);

    // lA hi/lo: [64][32] bf16 (4KB each); lB hi/lo: [128][18] uint (9216B each)
    ushort* lAh = (ushort*)smem;                    // 4096 B
    ushort* lAl = (ushort*)(smem + 4096);           // 4096 B
    uint*   lBh = (uint*)(smem + 8192);             // 9216 B
    uint*   lBl = (uint*)(smem + 17408);            // 9216 B  (total 26624)

    const int lane = tid & 63, w = tid >> 6;
    const int lr = lane & 15, lg = lane >> 4;
    const int wn = w * 32;
    const int lam = tid & 31;
    const int d0 = lam * 4;
    const int sp = tid >> 5;          // 0..7

    floatx4 acc[4][2];
#pragma unroll
    for (int m = 0; m < 4; ++m)
#pragma unroll
      for (int n = 0; n < 2; ++n) acc[m][n] = (floatx4){0.f, 0.f, 0.f, 0.f};

    for (int k0 = 0; k0 < S_; k0 += 32) {
      // stage A (dsm) hi/lo: one width-16 DMA per buffer covers [64][32]
      {
        size_t src = (size_t)(tid >> 2) * S_ + k0 + (size_t)(tid & 3) * 8;
        gload_lds16(Ah + src, lAh + w * 512);
        gload_lds16(Al + src, lAl + w * 512);
      }
      // load B tile: 32 s-rows x 128 d-cols, (s, s+1) pairs per thread
      float4 ra[2], rb[2];
#pragma unroll
      for (int si = 0; si < 2; ++si) {
        int s = sp * 2 + si * 16;
        const float* p = in + ((size_t)(b * S_ + k0 + s)) * D_ + c0 + d0;
        ra[si] = *(const float4*)p;
        rb[si] = *(const float4*)(p + D_);
      }
      const int swz = lam & 12;        // XOR on col bits 2-3 keeps b128 contig
#pragma unroll
      for (int si = 0; si < 2; ++si) {
        int col = (sp + si * 8) ^ swz;
        const float* pa = (const float*)&ra[si];
        const float* pb = (const float*)&rb[si];
#pragma unroll
        for (int i = 0; i < 4; ++i) {
          ushort h0 = f2bf(pa[i]);
          ushort l0 = f2bf(pa[i] - bf2f(h0));
          ushort h1 = f2bf(pb[i]);
          ushort l1 = f2bf(pb[i] - bf2f(h1));
          lBh[(d0 + i) * 18 + col] = (uint)h0 | ((uint)h1 << 16);
          lBl[(d0 + i) * 18 + col] = (uint)l0 | ((uint)l1 << 16);
        }
      }
      __syncthreads();
      short8 bh[2], bl[2];
#pragma unroll
      for (int n = 0; n < 2; ++n) {
        int d = wn + n * 16 + lr;
        int off = d * 18 + ((lg * 4) ^ ((d >> 2) & 12));
        bh[n] = *(const short8*)&lBh[off];
        bl[n] = *(const short8*)&lBl[off];
      }
#pragma unroll
      for (int m = 0; m < 4; ++m) {
        int aoff = (m * 16 + lr) * 32 + lg * 8;
        short8 ah = *(const short8*)&lAh[aoff];
        short8 al = *(const short8*)&lAl[aoff];
#pragma unroll
        for (int n = 0; n < 2; ++n) {
          acc[m][n] = __builtin_amdgcn_mfma_f32_16x16x32_bf16(ah, bh[n], acc[m][n], 0, 0, 0);
          acc[m][n] = __builtin_amdgcn_mfma_f32_16x16x32_bf16(ah, bl[n], acc[m][n], 0, 0, 0);
          acc[m][n] = __builtin_amdgcn_mfma_f32_16x16x32_bf16(al, bh[n], acc[m][n], 0, 0, 0);
        }
      }
      __syncthreads();
    }
    size_t obase = (size_t)b * KD_ * D_;
#pragma unroll
    for (int m = 0; m < 4; ++m)
#pragma unroll
      for (int n = 0; n < 2; ++n)
#pragma unroll
        for (int r = 0; r < 4; ++r)
          out[obase + (size_t)(m * 16 + lg * 4 + r) * D_ + c0 + wn + n * 16 + lr] =
              f2bf(acc[m][n][r]);

  } else {
    // ================= transpose+convert kkm/vkm =========================
    const int blk2 = blk - 512;
    const int tz = blk2 >> 10;            // 0: kkm, 1: vkm
    const int rem = blk2 & 1023;
    const int tyb = rem >> 5;
    const int txb = rem & 31;
    const float* in = tz == 0 ? kkm : vkm;
    ushort* outp    = tz == 0 ? kkT : vkT;
    float (*tile)[33] = (float(*)[33])smem;
    const int tx = tid & 31, ty = tid >> 5;
    int x = txb * 32 + tx;
    int y0 = tyb * 32;
#pragma unroll
    for (int j = 0; j < 4; ++j)
      tile[ty + j * 8][tx] = in[(size_t)(y0 + ty + j * 8) * 1024 + x];
    __syncthreads();
    int x2 = tyb * 32 + tx;
    int y2 = txb * 32;
#pragma unroll
    for (int j = 0; j < 4; ++j)
      outp[(size_t)(y2 + ty + j * 8) * 1024 + x2] = f2bf(tile[tx][ty + j * 8]);
  }
}

// ---- K/V projection GEMM fused with {qkT transpose | query cvt} ---------
// R16: V-half output now written TRANSPOSED per batch: vpT[b][1024 hd][64 k]
// (bit-identical values, layout only) so the attention PV step can read V
// fragments coalesced from global and the sV LDS staging disappears.
__global__ __launch_bounds__(256) void gemm_kv_q(
    const ushort* __restrict__ A,     // kds (vds contiguous)
    const ushort* __restrict__ Bt,    // kkT
    const ushort* __restrict__ Bt2,   // vkT
    ushort* __restrict__ C,           // k_proj (normal layout)
    ushort* __restrict__ vpT,         // v_projT [32][1024][64]
    const float* __restrict__ qk, ushort* __restrict__ qkT,
    const float* __restrict__ query, ushort* __restrict__ q_bf) {
  __shared__ __align__(16) char smem[16384];
  const int blk = blockIdx.x;
  const int tid = threadIdx.x;

  if (blk < 256) {
    // ================= 128x128 m97-style GEMM (K/V proj) =================
    ushort* lA = (ushort*)smem;            // [128*32] bf16, 8KB
    ushort* lB = (ushort*)(smem + 8192);   // 8KB
    int xcd = blk & 7, slot = blk >> 3;
    int mt = xcd * 4 + (slot >> 3);        // MT=32
    int nt = slot & 7;
    int m0 = mt * 128, n0 = nt * 128;
    const ushort* Bsel = (mt >= 16) ? Bt2 : Bt;

    int lane = tid & 63, w = tid >> 6;
    int lr = lane & 15, lg = lane >> 4;
    int wm = (w >> 1) * 64, wn = (w & 1) * 64;
    floatx4 acc[4][4];
#pragma unroll
    for (int m = 0; m < 4; ++m)
#pragma unroll
      for (int n = 0; n < 4; ++n) acc[m][n] = (floatx4){0.f, 0.f, 0.f, 0.f};

    for (int k0 = 0; k0 < 1024; k0 += 32) {
#pragma unroll
      for (int i = 0; i < 2; ++i) {
        int c = i * 256 + w * 64 + lane;
        gload_lds16(A + ((size_t)(m0 + (c >> 2)) * 1024 + k0 + (c & 3) * 8),
                    &lA[(i * 256 + w * 64) * 8]);
        gload_lds16(Bsel + ((size_t)(n0 + (c >> 2)) * 1024 + k0 + (c & 3) * 8),
                    &lB[(i * 256 + w * 64) * 8]);
      }
      __syncthreads();
      short8 af[4], bfr[4];
#pragma unroll
      for (int m = 0; m < 4; ++m)
        af[m] = *(const short8*)&lA[(wm + m * 16 + lr) * 32 + lg * 8];
#pragma unroll
      for (int n = 0; n < 4; ++n)
        bfr[n] = *(const short8*)&lB[(wn + n * 16 + lr) * 32 + lg * 8];
#pragma unroll
      for (int m = 0; m < 4; ++m)
#pragma unroll
        for (int n = 0; n < 4; ++n)
          acc[m][n] = __builtin_amdgcn_mfma_f32_16x16x32_bf16(af[m], bfr[n], acc[m][n], 0, 0, 0);
      __syncthreads();
    }
    if (mt < 16) {
      // K half: normal [b*64+k][1024] layout
#pragma unroll
      for (int m = 0; m < 4; ++m)
#pragma unroll
        for (int n = 0; n < 4; ++n)
#pragma unroll
          for (int r = 0; r < 4; ++r)
            C[(size_t)(m0 + wm + m * 16 + lg * 4 + r) * 1024 + n0 + wn + n * 16 + lr] =
                f2bf(acc[m][n][r]);
    } else {
      // V half: transposed vpT[b][hd][k]; r-consecutive = k-consecutive
#pragma unroll
      for (int m = 0; m < 4; ++m)
#pragma unroll
        for (int n = 0; n < 4; ++n) {
          int rowV = m0 - 2048 + wm + m * 16 + lg * 4;
          int b = rowV >> 6, k = rowV & 63;
          int hd = n0 + wn + n * 16 + lr;
          ushort4 o;
          o.x = f2bf(acc[m][n][0]); o.y = f2bf(acc[m][n][1]);
          o.z = f2bf(acc[m][n][2]); o.w = f2bf(acc[m][n][3]);
          *(ushort4*)&vpT[(size_t)b * 65536 + (size_t)hd * 64 + k] = o;
        }
    }

  } else if (blk < 256 + 1024) {
    // ================= transpose+convert qk -> qkT =======================
    const int blk2 = blk - 256;
    const int tyb = blk2 >> 5;
    const int txb = blk2 & 31;
    float (*tile)[33] = (float(*)[33])smem;
    const int tx = tid & 31, ty = tid >> 5;
    int x = txb * 32 + tx;
    int y0 = tyb * 32;
#pragma unroll
    for (int j = 0; j < 4; ++j)
      tile[ty + j * 8][tx] = qk[(size_t)(y0 + ty + j * 8) * 1024 + x];
    __syncthreads();
    int x2 = tyb * 32 + tx;
    int y2 = txb * 32;
#pragma unroll
    for (int j = 0; j < 4; ++j)
      qkT[(size_t)(y2 + ty + j * 8) * 1024 + x2] = f2bf(tile[tx][ty + j * 8]);

  } else {
    // ================= fp32 -> bf16 convert (query), coarsened ============
    const size_t base = (size_t)(blk - 1280) * 2048 + tid;
#pragma unroll
    for (int j = 0; j < 8; ++j) {
      size_t i = base + (size_t)j * 256;
      float4 v = ((const float4*)query)[i];
      ushort4 o;
      o.x = f2bf(v.x); o.y = f2bf(v.y); o.z = f2bf(v.z); o.w = f2bf(v.w);
      ((ushort4*)q_bf)[i] = o;
    }
  }
}

// ---- fused Q-projection (256x256) + attention, 16-wave reshape ----------
// R16: 8 waves x 128x64 -> 16 waves x 64x64 per wave (1024 threads).
// Rationale: old shape had acc(128) + ~120 VGPR = 248/256 budget -> stuck at
// 2 waves/SIMD with zero headroom, MfmaUtil 26%. New shape: acc=64 regs,
// total ~110-125 -> 4 waves/SIMD, double the latency-hiding wave pool, and
// per-wave ds_reads drop 28->16 per K-tile. Tail: each wave owns 64 s-rows
// x 1 head; per-wave QP 8KB XOR-swizzled (16x8KB = full 128KB overlay); V
// read direct from global vpT (coalesced), sV staging deleted.
__global__ __launch_bounds__(1024) void gemm256_attn(
    const ushort* __restrict__ A, const ushort* __restrict__ Bt,
    const ushort* __restrict__ kp, const ushort* __restrict__ vpT,
    float* __restrict__ out) {
  extern __shared__ ushort lds[];
  ushort* ldsA = lds;                   // [2][256*64]
  ushort* ldsB = lds + 2 * 256 * 64;    // [2][256*64]
  const int tid = threadIdx.x;
  const int w = tid >> 6, lane = tid & 63;
  const int lr = lane & 15, lg = lane >> 4;
  const int wm = w >> 2, wn = w & 3;    // 4 x 4 waves
  const int bid = blockIdx.x;
  const int mt = (bid & 7) * 8 + ((bid >> 3) >> 2);   // 0..63
  const int nt = (bid >> 3) & 3;
  const int m0 = mt * 256, n0 = nt * 256;
  const int NT = 16;                    // K=1024 / 64

  const int srow = tid >> 3;            // 0..127
  const int sslot = tid & 7;

  // stage one 128-row x 64-col chunk (ch=0,1) of A or B for buffer sl
  auto stageA = [&](int sl, int ch, int k0) {
    int rloc = ch * 128 + srow;
    int gs = sslot ^ (rloc & 7);
    gload_lds16(A + (size_t)(m0 + rloc) * 1024 + k0 + gs * 8,
                ldsA + sl * (256 * 64) + ch * (128 * 64) + w * 512);
  };
  auto stageB = [&](int sl, int ch, int k0) {
    int rloc = ch * 128 + srow;
    int gs = sslot ^ (rloc & 7);
    gload_lds16(Bt + (size_t)(n0 + rloc) * 1024 + k0 + gs * 8,
                ldsB + sl * (256 * 64) + ch * (128 * 64) + w * 512);
  };

  short8 af[2][2], bf[2][2];
  auto loadA = [&](int sl, int mh) {
#pragma unroll
    for (int i = 0; i < 2; ++i) {
      int row = wm * 64 + (mh * 2 + i) * 16 + lr;
#pragma unroll
      for (int kk = 0; kk < 2; ++kk) {
        int col = (((kk * 4 + lg) ^ (row & 7)) * 8);
        af[i][kk] = *(const short8*)&ldsA[sl * (256 * 64) + row * 64 + col];
      }
    }
  };
  auto loadB = [&](int sl, int nh) {
#pragma unroll
    for (int j = 0; j < 2; ++j) {
      int row = wn * 64 + (nh * 2 + j) * 16 + lr;
#pragma unroll
      for (int kk = 0; kk < 2; ++kk) {
        int col = (((kk * 4 + lg) ^ (row & 7)) * 8);
        bf[j][kk] = *(const short8*)&ldsB[sl * (256 * 64) + row * 64 + col];
      }
    }
  };

  floatx4 acc[4][4];
#pragma unroll
  for (int i = 0; i < 4; ++i)
#pragma unroll
    for (int j = 0; j < 4; ++j) acc[i][j] = (floatx4){0.f, 0.f, 0.f, 0.f};

  auto mma8 = [&](int mh, int nh) {
    __builtin_amdgcn_s_setprio(1);
#pragma unroll
    for (int i = 0; i < 2; ++i)
#pragma unroll
      for (int j = 0; j < 2; ++j)
#pragma unroll
        for (int kk = 0; kk < 2; ++kk)
          acc[mh * 2 + i][nh * 2 + j] = __builtin_amdgcn_mfma_f32_16x16x32_bf16(
              af[i][kk], bf[j][kk], acc[mh * 2 + i][nh * 2 + j], 0, 0, 0);
    __builtin_amdgcn_s_setprio(0);
  };

  // prologue: stage tile 0 (4 chunks)
  stageA(0, 0, 0); stageA(0, 1, 0); stageB(0, 0, 0); stageB(0, 1, 0);

#pragma unroll 2
  for (int t = 0; t < NT; ++t) {
    const int s = t & 1, ns = s ^ 1;
    const int kn = (t + 1) << 6;
    const bool more = (t + 1 < NT);
    // counted wait: drains buf[s]'s chunks, keeps the just-issued one
    if (more) { stageA(ns, 0, kn); asm volatile("s_waitcnt vmcnt(1)" ::: "memory"); }
    else      { asm volatile("s_waitcnt vmcnt(0)" ::: "memory"); }
    BARRIER();
    loadA(s, 0); loadB(s, 0);
    WAITLGKM();
    mma8(0, 0);
    BARRIER();
    if (more) stageA(ns, 1, kn);
    loadB(s, 1);
    BARRIER();
    WAITLGKM();
    mma8(0, 1);
    BARRIER();
    if (more) stageB(ns, 0, kn);
    loadA(s, 1);
    BARRIER();
    WAITLGKM();
    mma8(1, 1);
    BARRIER();
    if (more) stageB(ns, 1, kn);
    loadB(s, 0);
    BARRIER();
    WAITLGKM();
    mma8(1, 0);
    BARRIER();
  }
  // After the final BARRIER all LDS activity is drained: buffers reusable.

  // ================= attention tail (wave-private, no block sync) =========
  // QP per wave: [64][64] bf16, XOR-swizzled (col-block ^ row&7), 8KB.
  ushort* QP = lds + w * 4096;
  const int b = mt >> 1;
  const int hq = nt * 4 + wn;           // this wave's head
  const int srow0 = (mt & 1) * 256 + wm * 64;

  // ---- write Q tile (from acc, swizzled) ----
#pragma unroll
  for (int mi = 0; mi < 4; ++mi)
#pragma unroll
    for (int nj = 0; nj < 4; ++nj)
#pragma unroll
      for (int r = 0; r < 4; ++r) {
        int row = mi * 16 + lg * 4 + r, col = nj * 16 + lr;
        QP[row * 64 + ((((col >> 3) ^ (row & 7)) << 3) | (col & 7))] =
            f2bf(acc[mi][nj][r]);
      }
  WAITLGKM();
  __builtin_amdgcn_sched_barrier(0);
  // ---- QK^T: Q from LDS, K from global (L2-hot) ----
  floatx4 qacc[4][4];
#pragma unroll
  for (int m = 0; m < 4; ++m)
#pragma unroll
    for (int n = 0; n < 4; ++n) qacc[m][n] = (floatx4){0.f, 0.f, 0.f, 0.f};
#pragma unroll
  for (int kk = 0; kk < 2; ++kk) {
    short8 qa[4], kb[4];
#pragma unroll
    for (int m = 0; m < 4; ++m) {
      int row = m * 16 + lr;
      qa[m] = *(const short8*)&QP[row * 64 + (((kk * 4 + lg) ^ (row & 7)) << 3)];
    }
#pragma unroll
    for (int n = 0; n < 4; ++n)
      kb[n] = *(const short8*)(kp + ((size_t)b * KD_ + n * 16 + lr) * 1024 +
                               hq * HD_ + kk * 32 + lg * 8);
#pragma unroll
    for (int m = 0; m < 4; ++m)
#pragma unroll
      for (int n = 0; n < 4; ++n)
        qacc[m][n] = __builtin_amdgcn_mfma_f32_16x16x32_bf16(qa[m], kb[n], qacc[m][n], 0, 0, 0);
  }
  // ---- mask + softmax ----
#pragma unroll
  for (int m = 0; m < 4; ++m) {
#pragma unroll
    for (int r = 0; r < 4; ++r) {
      int srow2 = srow0 + m * 16 + lg * 4 + r;
      float vals[4];
      float mx = -1e30f;
#pragma unroll
      for (int n = 0; n < 4; ++n) {
        int col = n * 16 + lr;
        float val = qacc[m][n][r];
        val = (col <= srow2) ? val : -1e30f;
        vals[n] = val;
        mx = fmaxf(mx, val);
      }
      mx = fmaxf(mx, __shfl_xor(mx, 1));
      mx = fmaxf(mx, __shfl_xor(mx, 2));
      mx = fmaxf(mx, __shfl_xor(mx, 4));
      mx = fmaxf(mx, __shfl_xor(mx, 8));
      float sum = 0.f;
#pragma unroll
      for (int n = 0; n < 4; ++n) {
        float e = __expf(vals[n] - mx);
        vals[n] = e;
        sum += e;
      }
      sum += __shfl_xor(sum, 1);
      sum += __shfl_xor(sum, 2);
      sum += __shfl_xor(sum, 4);
      sum += __shfl_xor(sum, 8);
      float inv = 1.0f / sum;
#pragma unroll
      for (int n = 0; n < 4; ++n) {
        int row = m * 16 + lg * 4 + r, col = n * 16 + lr;
        QP[row * 64 + ((((col >> 3) ^ (row & 7)) << 3) | (col & 7))] =
            f2bf(vals[n] * inv);
      }
    }
  }
  WAITLGKM();
  __builtin_amdgcn_sched_barrier(0);
  // ---- PV: P from LDS, V from global transposed vpT[b][hd][k] ----
  floatx4 oacc[4][4];
#pragma unroll
  for (int m = 0; m < 4; ++m)
#pragma unroll
    for (int n = 0; n < 4; ++n) oacc[m][n] = (floatx4){0.f, 0.f, 0.f, 0.f};
#pragma unroll
  for (int kk = 0; kk < 2; ++kk) {
    short8 pa[4], vb[4];
#pragma unroll
    for (int m = 0; m < 4; ++m) {
      int row = m * 16 + lr;
      pa[m] = *(const short8*)&QP[row * 64 + (((kk * 4 + lg) ^ (row & 7)) << 3)];
    }
#pragma unroll
    for (int n = 0; n < 4; ++n)
      vb[n] = *(const short8*)(vpT + (size_t)b * 65536 +
                               (size_t)(hq * HD_ + n * 16 + lr) * 64 +
                               kk * 32 + lg * 8);
#pragma unroll
    for (int m = 0; m < 4; ++m)
#pragma unroll
      for (int n = 0; n < 4; ++n)
        oacc[m][n] = __builtin_amdgcn_mfma_f32_16x16x32_bf16(pa[m], vb[n], oacc[m][n], 0, 0, 0);
  }
#pragma unroll
  for (int m = 0; m < 4; ++m)
#pragma unroll
    for (int n = 0; n < 4; ++n)
#pragma unroll
      for (int r = 0; r < 4; ++r)
        out[((size_t)b * S_ + srow0 + m * 16 + lg * 4 + r) * 1024 +
            hq * HD_ + n * 16 + lr] = oacc[m][n][r];
}

// ------------------------------- launcher ---------------------------------
extern "C" void kernel_launch(void* const* d_in, const int* in_sizes, int n_in,
                              void* d_out, int out_size, void* d_ws, size_t ws_size,
                              hipStream_t stream) {
  const float* query = (const float*)d_in[0];
  const float* key   = (const float*)d_in[1];
  const float* value = (const float*)d_in[2];
  const float* qk    = (const float*)d_in[3];
  const float* kk    = (const float*)d_in[4];
  const float* vk    = (const float*)d_in[5];
  const float* kdm   = (const float*)d_in[6];
  const float* vdm   = (const float*)d_in[7];
  float* out = (float*)d_out;

  char* ws = (char*)d_ws;
  if (ws_size < (90ull << 20)) return;
  ushort* q_bf   = (ushort*)(ws);                    // 32 MB  [16384][1024]
  ushort* qkT    = (ushort*)(ws + (33ull << 20));    //  2 MB  [1024][1024]
  ushort* kkT    = (ushort*)(ws + (35ull << 20));
  ushort* vkT    = (ushort*)(ws + (37ull << 20));
  ushort* kds    = (ushort*)(ws + (39ull << 20));    //  4 MB  [2048][1024]
  ushort* vds    = (ushort*)(ws + (43ull << 20));    //  (contiguous with kds)
  ushort* k_proj = (ushort*)(ws + (79ull << 20));    //  4 MB  [2048][1024]
  ushort* v_projT= (ushort*)(ws + (83ull << 20));    //  4 MB  [32][1024][64]
  ushort* dsm_hi = (ushort*)(ws + (87ull << 20));    // 128 KB [2][64][512]
  ushort* dsm_lo = (ushort*)(ws + (87ull << 20) + (128ull << 10));

  hipFuncSetAttribute((const void*)gemm256_attn,
                      hipFuncAttributeMaxDynamicSharedMemorySize, 131072);

  cvt_split<<<64, 256, 0, stream>>>(kdm, vdm, dsm_hi, dsm_lo);
  // K/V path: ds(512, XCD-grouped) | transpose kkT/vkT(2048)
  pre_kv<<<512 + 2048, 256, 0, stream>>>(
      key, value, kk, vk, dsm_hi, dsm_lo, kkT, vkT, kds, vds);
  // K+V projections + {qkT transpose | query cvt} streaming underneath
  gemm_kv_q<<<256 + 1024 + 2048, 256, 0, stream>>>(
      kds, kkT, vkT, k_proj, v_projT, qk, qkT, query, q_bf);
  // Q projection + attention fused, 16-wave shape
  gemm256_attn<<<256, 1024, 131072, stream>>>(q_bf, qkT, k_proj, v_projT, out);
}

// Round 5
// 152.481 us; speedup vs baseline: 1.0007x; 1.0007x over previous
//
#include <hip/hip_runtime.h>
#include <stdint.h>

// Problem constants
#define B_   32
#define S_   512
#define D_   1024
#define H_   16
#define HD_  64
#define KD_  64
#define NH_  1024   // H*HD

typedef __attribute__((ext_vector_type(8))) short short8;
typedef __attribute__((ext_vector_type(4))) float floatx4;

#define GAS __attribute__((address_space(1)))
#define LAS __attribute__((address_space(3)))

__device__ __forceinline__ ushort f2bf(float f) {
  uint32_t u = __float_as_uint(f);
  u = u + 0x7FFFu + ((u >> 16) & 1u);   // round-to-nearest-even
  return (ushort)(u >> 16);
}

__device__ __forceinline__ float bf2f(ushort h) {
  return __uint_as_float(((uint32_t)h) << 16);
}

__device__ __forceinline__ void gload_lds16(const void* g, void* l) {
  // width=16 global->LDS DMA; LDS dest is wave-uniform base + lane*16
  __builtin_amdgcn_global_load_lds((const GAS uint32_t*)g, (LAS uint32_t*)l, 16, 0, 0);
}

#define BARRIER() asm volatile("s_barrier" ::: "memory")
#define WAITLGKM() asm volatile("s_waitcnt lgkmcnt(0)" ::: "memory")

// ---- split-convert the two downsample mats to hi/lo bf16: [2][64][512] ---
__global__ __launch_bounds__(256) void cvt_split(const float* __restrict__ kdm,
                                                 const float* __restrict__ vdm,
                                                 ushort* __restrict__ hi,
                                                 ushort* __restrict__ lo) {
  int i = blockIdx.x * 256 + threadIdx.x;        // 16384 float4s total
  const float* src = (i < 8192) ? kdm : vdm;
  int j = i & 8191;
  float4 v = ((const float4*)src)[j];
  ushort4 h, l;
  h.x = f2bf(v.x); l.x = f2bf(v.x - bf2f(h.x));
  h.y = f2bf(v.y); l.y = f2bf(v.y - bf2f(h.y));
  h.z = f2bf(v.z); l.z = f2bf(v.z - bf2f(h.z));
  h.w = f2bf(v.w); l.w = f2bf(v.w - bf2f(h.w));
  ((ushort4*)hi)[i] = h;
  ((ushort4*)lo)[i] = l;
}

// ---- R14: pre_kv = {downsample(512) | transpose kkT/vkT(2048)} ----------
__global__ __launch_bounds__(256, 6) void pre_kv(
    const float* __restrict__ key, const float* __restrict__ value,
    const float* __restrict__ kkm, const float* __restrict__ vkm,
    const ushort* __restrict__ dsm_hi, const ushort* __restrict__ dsm_lo,
    ushort* __restrict__ kkT, ushort* __restrict__ vkT,
    ushort* __restrict__ outk, ushort* __restrict__ outv) {
  __shared__ __align__(16) char smem[26624];
  const int blk = blockIdx.x;
  const int tid = threadIdx.x;

  if (blk < 512) {
    // ================= downsample (32-wide s-chunks) ======================
    const int bz = (blk & 7) + ((blk >> 6) << 3);
    const int t  = (blk >> 3) & 7;
    const int z = bz >> 5, b = bz & 31;
    const int c0 = t * 128;
    const float* in = z ? value : key;
    ushort* out     = z ? outv : outk;
    const ushort* Ah = dsm_hi + (size_t)z * (KD_ * S_);
    const ushort* Al = dsm_lo + (size_t)z * (KD_ * S_);

    // lA hi/lo: [64][32] bf16 (4KB each); lB hi/lo: [128][18] uint (9216B each)
    ushort* lAh = (ushort*)smem;                    // 4096 B
    ushort* lAl = (ushort*)(smem + 4096);           // 4096 B
    uint*   lBh = (uint*)(smem + 8192);             // 9216 B
    uint*   lBl = (uint*)(smem + 17408);            // 9216 B  (total 26624)

    const int lane = tid & 63, w = tid >> 6;
    const int lr = lane & 15, lg = lane >> 4;
    const int wn = w * 32;
    const int lam = tid & 31;
    const int d0 = lam * 4;
    const int sp = tid >> 5;          // 0..7

    floatx4 acc[4][2];
#pragma unroll
    for (int m = 0; m < 4; ++m)
#pragma unroll
      for (int n = 0; n < 2; ++n) acc[m][n] = (floatx4){0.f, 0.f, 0.f, 0.f};

    for (int k0 = 0; k0 < S_; k0 += 32) {
      // stage A (dsm) hi/lo: one width-16 DMA per buffer covers [64][32]
      {
        size_t src = (size_t)(tid >> 2) * S_ + k0 + (size_t)(tid & 3) * 8;
        gload_lds16(Ah + src, lAh + w * 512);
        gload_lds16(Al + src, lAl + w * 512);
      }
      // load B tile: 32 s-rows x 128 d-cols, (s, s+1) pairs per thread
      float4 ra[2], rb[2];
#pragma unroll
      for (int si = 0; si < 2; ++si) {
        int s = sp * 2 + si * 16;
        const float* p = in + ((size_t)(b * S_ + k0 + s)) * D_ + c0 + d0;
        ra[si] = *(const float4*)p;
        rb[si] = *(const float4*)(p + D_);
      }
      const int swz = lam & 12;        // XOR on col bits 2-3 keeps b128 contig
#pragma unroll
      for (int si = 0; si < 2; ++si) {
        int col = (sp + si * 8) ^ swz;
        const float* pa = (const float*)&ra[si];
        const float* pb = (const float*)&rb[si];
#pragma unroll
        for (int i = 0; i < 4; ++i) {
          ushort h0 = f2bf(pa[i]);
          ushort l0 = f2bf(pa[i] - bf2f(h0));
          ushort h1 = f2bf(pb[i]);
          ushort l1 = f2bf(pb[i] - bf2f(h1));
          lBh[(d0 + i) * 18 + col] = (uint)h0 | ((uint)h1 << 16);
          lBl[(d0 + i) * 18 + col] = (uint)l0 | ((uint)l1 << 16);
        }
      }
      __syncthreads();
      short8 bh[2], bl[2];
#pragma unroll
      for (int n = 0; n < 2; ++n) {
        int d = wn + n * 16 + lr;
        int off = d * 18 + ((lg * 4) ^ ((d >> 2) & 12));
        bh[n] = *(const short8*)&lBh[off];
        bl[n] = *(const short8*)&lBl[off];
      }
#pragma unroll
      for (int m = 0; m < 4; ++m) {
        int aoff = (m * 16 + lr) * 32 + lg * 8;
        short8 ah = *(const short8*)&lAh[aoff];
        short8 al = *(const short8*)&lAl[aoff];
#pragma unroll
        for (int n = 0; n < 2; ++n) {
          acc[m][n] = __builtin_amdgcn_mfma_f32_16x16x32_bf16(ah, bh[n], acc[m][n], 0, 0, 0);
          acc[m][n] = __builtin_amdgcn_mfma_f32_16x16x32_bf16(ah, bl[n], acc[m][n], 0, 0, 0);
          acc[m][n] = __builtin_amdgcn_mfma_f32_16x16x32_bf16(al, bh[n], acc[m][n], 0, 0, 0);
        }
      }
      __syncthreads();
    }
    size_t obase = (size_t)b * KD_ * D_;
#pragma unroll
    for (int m = 0; m < 4; ++m)
#pragma unroll
      for (int n = 0; n < 2; ++n)
#pragma unroll
        for (int r = 0; r < 4; ++r)
          out[obase + (size_t)(m * 16 + lg * 4 + r) * D_ + c0 + wn + n * 16 + lr] =
              f2bf(acc[m][n][r]);

  } else {
    // ================= transpose+convert kkm/vkm =========================
    const int blk2 = blk - 512;
    const int tz = blk2 >> 10;            // 0: kkm, 1: vkm
    const int rem = blk2 & 1023;
    const int tyb = rem >> 5;
    const int txb = rem & 31;
    const float* in = tz == 0 ? kkm : vkm;
    ushort* outp    = tz == 0 ? kkT : vkT;
    float (*tile)[33] = (float(*)[33])smem;
    const int tx = tid & 31, ty = tid >> 5;
    int x = txb * 32 + tx;
    int y0 = tyb * 32;
#pragma unroll
    for (int j = 0; j < 4; ++j)
      tile[ty + j * 8][tx] = in[(size_t)(y0 + ty + j * 8) * 1024 + x];
    __syncthreads();
    int x2 = tyb * 32 + tx;
    int y2 = txb * 32;
#pragma unroll
    for (int j = 0; j < 4; ++j)
      outp[(size_t)(y2 + ty + j * 8) * 1024 + x2] = f2bf(tile[tx][ty + j * 8]);
  }
}

// ---- K/V projection GEMM fused with {qkT transpose | query cvt} ---------
// R16: V-half output written TRANSPOSED per batch: vpT[b][1024 hd][64 k]
// (bit-identical values, layout only) so the attention PV step can read V
// fragments coalesced from global and the sV LDS staging disappears.
__global__ __launch_bounds__(256) void gemm_kv_q(
    const ushort* __restrict__ A,     // kds (vds contiguous)
    const ushort* __restrict__ Bt,    // kkT
    const ushort* __restrict__ Bt2,   // vkT
    ushort* __restrict__ C,           // k_proj (normal layout)
    ushort* __restrict__ vpT,         // v_projT [32][1024][64]
    const float* __restrict__ qk, ushort* __restrict__ qkT,
    const float* __restrict__ query, ushort* __restrict__ q_bf) {
  __shared__ __align__(16) char smem[16384];
  const int blk = blockIdx.x;
  const int tid = threadIdx.x;

  if (blk < 256) {
    // ================= 128x128 m97-style GEMM (K/V proj) =================
    ushort* lA = (ushort*)smem;            // [128*32] bf16, 8KB
    ushort* lB = (ushort*)(smem + 8192);   // 8KB
    int xcd = blk & 7, slot = blk >> 3;
    int mt = xcd * 4 + (slot >> 3);        // MT=32
    int nt = slot & 7;
    int m0 = mt * 128, n0 = nt * 128;
    const ushort* Bsel = (mt >= 16) ? Bt2 : Bt;

    int lane = tid & 63, w = tid >> 6;
    int lr = lane & 15, lg = lane >> 4;
    int wm = (w >> 1) * 64, wn = (w & 1) * 64;
    floatx4 acc[4][4];
#pragma unroll
    for (int m = 0; m < 4; ++m)
#pragma unroll
      for (int n = 0; n < 4; ++n) acc[m][n] = (floatx4){0.f, 0.f, 0.f, 0.f};

    for (int k0 = 0; k0 < 1024; k0 += 32) {
#pragma unroll
      for (int i = 0; i < 2; ++i) {
        int c = i * 256 + w * 64 + lane;
        gload_lds16(A + ((size_t)(m0 + (c >> 2)) * 1024 + k0 + (c & 3) * 8),
                    &lA[(i * 256 + w * 64) * 8]);
        gload_lds16(Bsel + ((size_t)(n0 + (c >> 2)) * 1024 + k0 + (c & 3) * 8),
                    &lB[(i * 256 + w * 64) * 8]);
      }
      __syncthreads();
      short8 af[4], bfr[4];
#pragma unroll
      for (int m = 0; m < 4; ++m)
        af[m] = *(const short8*)&lA[(wm + m * 16 + lr) * 32 + lg * 8];
#pragma unroll
      for (int n = 0; n < 4; ++n)
        bfr[n] = *(const short8*)&lB[(wn + n * 16 + lr) * 32 + lg * 8];
#pragma unroll
      for (int m = 0; m < 4; ++m)
#pragma unroll
        for (int n = 0; n < 4; ++n)
          acc[m][n] = __builtin_amdgcn_mfma_f32_16x16x32_bf16(af[m], bfr[n], acc[m][n], 0, 0, 0);
      __syncthreads();
    }
    if (mt < 16) {
      // K half: normal [b*64+k][1024] layout
#pragma unroll
      for (int m = 0; m < 4; ++m)
#pragma unroll
        for (int n = 0; n < 4; ++n)
#pragma unroll
          for (int r = 0; r < 4; ++r)
            C[(size_t)(m0 + wm + m * 16 + lg * 4 + r) * 1024 + n0 + wn + n * 16 + lr] =
                f2bf(acc[m][n][r]);
    } else {
      // V half: transposed vpT[b][hd][k]; r-consecutive = k-consecutive
#pragma unroll
      for (int m = 0; m < 4; ++m)
#pragma unroll
        for (int n = 0; n < 4; ++n) {
          int rowV = m0 - 2048 + wm + m * 16 + lg * 4;
          int b = rowV >> 6, k = rowV & 63;
          int hd = n0 + wn + n * 16 + lr;
          ushort4 o;
          o.x = f2bf(acc[m][n][0]); o.y = f2bf(acc[m][n][1]);
          o.z = f2bf(acc[m][n][2]); o.w = f2bf(acc[m][n][3]);
          *(ushort4*)&vpT[(size_t)b * 65536 + (size_t)hd * 64 + k] = o;
        }
    }

  } else if (blk < 256 + 1024) {
    // ================= transpose+convert qk -> qkT =======================
    const int blk2 = blk - 256;
    const int tyb = blk2 >> 5;
    const int txb = blk2 & 31;
    float (*tile)[33] = (float(*)[33])smem;
    const int tx = tid & 31, ty = tid >> 5;
    int x = txb * 32 + tx;
    int y0 = tyb * 32;
#pragma unroll
    for (int j = 0; j < 4; ++j)
      tile[ty + j * 8][tx] = qk[(size_t)(y0 + ty + j * 8) * 1024 + x];
    __syncthreads();
    int x2 = tyb * 32 + tx;
    int y2 = txb * 32;
#pragma unroll
    for (int j = 0; j < 4; ++j)
      qkT[(size_t)(y2 + ty + j * 8) * 1024 + x2] = f2bf(tile[tx][ty + j * 8]);

  } else {
    // ================= fp32 -> bf16 convert (query), coarsened ============
    const size_t base = (size_t)(blk - 1280) * 2048 + tid;
#pragma unroll
    for (int j = 0; j < 8; ++j) {
      size_t i = base + (size_t)j * 256;
      float4 v = ((const float4*)query)[i];
      ushort4 o;
      o.x = f2bf(v.x); o.y = f2bf(v.y); o.z = f2bf(v.z); o.w = f2bf(v.w);
      ((ushort4*)q_bf)[i] = o;
    }
  }
}

// ---- fused Q-projection (256x256) + attention, 16-wave shape ------------
// R17: R16's reshape was sabotaged by the register allocator — without a
// waves/EU declaration the compiler capped VGPRs at 64 (acc[4][4] alone is
// 64) and spilled the accumulators to scratch: WRITE_SIZE 66->132MB,
// FETCH 30->63MB, MfmaUtil 19%. LDS already pins us at 1 block/CU =
// 4 waves/SIMD, so declare __launch_bounds__(1024, 4) -> 128-VGPR cap,
// which fits acc(64)+frags(16)+addressing (~120 peak; acc dies before
// qacc is born). Everything else byte-identical to R16.
__global__ __launch_bounds__(1024, 4) void gemm256_attn(
    const ushort* __restrict__ A, const ushort* __restrict__ Bt,
    const ushort* __restrict__ kp, const ushort* __restrict__ vpT,
    float* __restrict__ out) {
  extern __shared__ ushort lds[];
  ushort* ldsA = lds;                   // [2][256*64]
  ushort* ldsB = lds + 2 * 256 * 64;    // [2][256*64]
  const int tid = threadIdx.x;
  const int w = tid >> 6, lane = tid & 63;
  const int lr = lane & 15, lg = lane >> 4;
  const int wm = w >> 2, wn = w & 3;    // 4 x 4 waves
  const int bid = blockIdx.x;
  const int mt = (bid & 7) * 8 + ((bid >> 3) >> 2);   // 0..63
  const int nt = (bid >> 3) & 3;
  const int m0 = mt * 256, n0 = nt * 256;
  const int NT = 16;                    // K=1024 / 64

  const int srow = tid >> 3;            // 0..127
  const int sslot = tid & 7;

  // stage one 128-row x 64-col chunk (ch=0,1) of A or B for buffer sl
  auto stageA = [&](int sl, int ch, int k0) {
    int rloc = ch * 128 + srow;
    int gs = sslot ^ (rloc & 7);
    gload_lds16(A + (size_t)(m0 + rloc) * 1024 + k0 + gs * 8,
                ldsA + sl * (256 * 64) + ch * (128 * 64) + w * 512);
  };
  auto stageB = [&](int sl, int ch, int k0) {
    int rloc = ch * 128 + srow;
    int gs = sslot ^ (rloc & 7);
    gload_lds16(Bt + (size_t)(n0 + rloc) * 1024 + k0 + gs * 8,
                ldsB + sl * (256 * 64) + ch * (128 * 64) + w * 512);
  };

  short8 af[2][2], bf[2][2];
  auto loadA = [&](int sl, int mh) {
#pragma unroll
    for (int i = 0; i < 2; ++i) {
      int row = wm * 64 + (mh * 2 + i) * 16 + lr;
#pragma unroll
      for (int kk = 0; kk < 2; ++kk) {
        int col = (((kk * 4 + lg) ^ (row & 7)) * 8);
        af[i][kk] = *(const short8*)&ldsA[sl * (256 * 64) + row * 64 + col];
      }
    }
  };
  auto loadB = [&](int sl, int nh) {
#pragma unroll
    for (int j = 0; j < 2; ++j) {
      int row = wn * 64 + (nh * 2 + j) * 16 + lr;
#pragma unroll
      for (int kk = 0; kk < 2; ++kk) {
        int col = (((kk * 4 + lg) ^ (row & 7)) * 8);
        bf[j][kk] = *(const short8*)&ldsB[sl * (256 * 64) + row * 64 + col];
      }
    }
  };

  floatx4 acc[4][4];
#pragma unroll
  for (int i = 0; i < 4; ++i)
#pragma unroll
    for (int j = 0; j < 4; ++j) acc[i][j] = (floatx4){0.f, 0.f, 0.f, 0.f};

  auto mma8 = [&](int mh, int nh) {
    __builtin_amdgcn_s_setprio(1);
#pragma unroll
    for (int i = 0; i < 2; ++i)
#pragma unroll
      for (int j = 0; j < 2; ++j)
#pragma unroll
        for (int kk = 0; kk < 2; ++kk)
          acc[mh * 2 + i][nh * 2 + j] = __builtin_amdgcn_mfma_f32_16x16x32_bf16(
              af[i][kk], bf[j][kk], acc[mh * 2 + i][nh * 2 + j], 0, 0, 0);
    __builtin_amdgcn_s_setprio(0);
  };

  // prologue: stage tile 0 (4 chunks)
  stageA(0, 0, 0); stageA(0, 1, 0); stageB(0, 0, 0); stageB(0, 1, 0);

#pragma unroll 2
  for (int t = 0; t < NT; ++t) {
    const int s = t & 1, ns = s ^ 1;
    const int kn = (t + 1) << 6;
    const bool more = (t + 1 < NT);
    // counted wait: drains buf[s]'s chunks, keeps the just-issued one
    if (more) { stageA(ns, 0, kn); asm volatile("s_waitcnt vmcnt(1)" ::: "memory"); }
    else      { asm volatile("s_waitcnt vmcnt(0)" ::: "memory"); }
    BARRIER();
    loadA(s, 0); loadB(s, 0);
    WAITLGKM();
    mma8(0, 0);
    BARRIER();
    if (more) stageA(ns, 1, kn);
    loadB(s, 1);
    BARRIER();
    WAITLGKM();
    mma8(0, 1);
    BARRIER();
    if (more) stageB(ns, 0, kn);
    loadA(s, 1);
    BARRIER();
    WAITLGKM();
    mma8(1, 1);
    BARRIER();
    if (more) stageB(ns, 1, kn);
    loadB(s, 0);
    BARRIER();
    WAITLGKM();
    mma8(1, 0);
    BARRIER();
  }
  // After the final BARRIER all LDS activity is drained: buffers reusable.

  // ================= attention tail (wave-private, no block sync) =========
  // QP per wave: [64][64] bf16, XOR-swizzled (col-block ^ row&7), 8KB.
  ushort* QP = lds + w * 4096;
  const int b = mt >> 1;
  const int hq = nt * 4 + wn;           // this wave's head
  const int srow0 = (mt & 1) * 256 + wm * 64;

  // ---- write Q tile (from acc, swizzled) ----
#pragma unroll
  for (int mi = 0; mi < 4; ++mi)
#pragma unroll
    for (int nj = 0; nj < 4; ++nj)
#pragma unroll
      for (int r = 0; r < 4; ++r) {
        int row = mi * 16 + lg * 4 + r, col = nj * 16 + lr;
        QP[row * 64 + ((((col >> 3) ^ (row & 7)) << 3) | (col & 7))] =
            f2bf(acc[mi][nj][r]);
      }
  WAITLGKM();
  __builtin_amdgcn_sched_barrier(0);
  // ---- QK^T: Q from LDS, K from global (L2-hot) ----
  floatx4 qacc[4][4];
#pragma unroll
  for (int m = 0; m < 4; ++m)
#pragma unroll
    for (int n = 0; n < 4; ++n) qacc[m][n] = (floatx4){0.f, 0.f, 0.f, 0.f};
#pragma unroll
  for (int kk = 0; kk < 2; ++kk) {
    short8 qa[4], kb[4];
#pragma unroll
    for (int m = 0; m < 4; ++m) {
      int row = m * 16 + lr;
      qa[m] = *(const short8*)&QP[row * 64 + (((kk * 4 + lg) ^ (row & 7)) << 3)];
    }
#pragma unroll
    for (int n = 0; n < 4; ++n)
      kb[n] = *(const short8*)(kp + ((size_t)b * KD_ + n * 16 + lr) * 1024 +
                               hq * HD_ + kk * 32 + lg * 8);
#pragma unroll
    for (int m = 0; m < 4; ++m)
#pragma unroll
      for (int n = 0; n < 4; ++n)
        qacc[m][n] = __builtin_amdgcn_mfma_f32_16x16x32_bf16(qa[m], kb[n], qacc[m][n], 0, 0, 0);
  }
  // ---- mask + softmax ----
#pragma unroll
  for (int m = 0; m < 4; ++m) {
#pragma unroll
    for (int r = 0; r < 4; ++r) {
      int srow2 = srow0 + m * 16 + lg * 4 + r;
      float vals[4];
      float mx = -1e30f;
#pragma unroll
      for (int n = 0; n < 4; ++n) {
        int col = n * 16 + lr;
        float val = qacc[m][n][r];
        val = (col <= srow2) ? val : -1e30f;
        vals[n] = val;
        mx = fmaxf(mx, val);
      }
      mx = fmaxf(mx, __shfl_xor(mx, 1));
      mx = fmaxf(mx, __shfl_xor(mx, 2));
      mx = fmaxf(mx, __shfl_xor(mx, 4));
      mx = fmaxf(mx, __shfl_xor(mx, 8));
      float sum = 0.f;
#pragma unroll
      for (int n = 0; n < 4; ++n) {
        float e = __expf(vals[n] - mx);
        vals[n] = e;
        sum += e;
      }
      sum += __shfl_xor(sum, 1);
      sum += __shfl_xor(sum, 2);
      sum += __shfl_xor(sum, 4);
      sum += __shfl_xor(sum, 8);
      float inv = 1.0f / sum;
#pragma unroll
      for (int n = 0; n < 4; ++n) {
        int row = m * 16 + lg * 4 + r, col = n * 16 + lr;
        QP[row * 64 + ((((col >> 3) ^ (row & 7)) << 3) | (col & 7))] =
            f2bf(vals[n] * inv);
      }
    }
  }
  WAITLGKM();
  __builtin_amdgcn_sched_barrier(0);
  // ---- PV: P from LDS, V from global transposed vpT[b][hd][k] ----
  floatx4 oacc[4][4];
#pragma unroll
  for (int m = 0; m < 4; ++m)
#pragma unroll
    for (int n = 0; n < 4; ++n) oacc[m][n] = (floatx4){0.f, 0.f, 0.f, 0.f};
#pragma unroll
  for (int kk = 0; kk < 2; ++kk) {
    short8 pa[4], vb[4];
#pragma unroll
    for (int m = 0; m < 4; ++m) {
      int row = m * 16 + lr;
      pa[m] = *(const short8*)&QP[row * 64 + (((kk * 4 + lg) ^ (row & 7)) << 3)];
    }
#pragma unroll
    for (int n = 0; n < 4; ++n)
      vb[n] = *(const short8*)(vpT + (size_t)b * 65536 +
                               (size_t)(hq * HD_ + n * 16 + lr) * 64 +
                               kk * 32 + lg * 8);
#pragma unroll
    for (int m = 0; m < 4; ++m)
#pragma unroll
      for (int n = 0; n < 4; ++n)
        oacc[m][n] = __builtin_amdgcn_mfma_f32_16x16x32_bf16(pa[m], vb[n], oacc[m][n], 0, 0, 0);
  }
#pragma unroll
  for (int m = 0; m < 4; ++m)
#pragma unroll
    for (int n = 0; n < 4; ++n)
#pragma unroll
      for (int r = 0; r < 4; ++r)
        out[((size_t)b * S_ + srow0 + m * 16 + lg * 4 + r) * 1024 +
            hq * HD_ + n * 16 + lr] = oacc[m][n][r];
}

// ------------------------------- launcher ---------------------------------
extern "C" void kernel_launch(void* const* d_in, const int* in_sizes, int n_in,
                              void* d_out, int out_size, void* d_ws, size_t ws_size,
                              hipStream_t stream) {
  const float* query = (const float*)d_in[0];
  const float* key   = (const float*)d_in[1];
  const float* value = (const float*)d_in[2];
  const float* qk    = (const float*)d_in[3];
  const float* kk    = (const float*)d_in[4];
  const float* vk    = (const float*)d_in[5];
  const float* kdm   = (const float*)d_in[6];
  const float* vdm   = (const float*)d_in[7];
  float* out = (float*)d_out;

  char* ws = (char*)d_ws;
  if (ws_size < (90ull << 20)) return;
  ushort* q_bf   = (ushort*)(ws);                    // 32 MB  [16384][1024]
  ushort* qkT    = (ushort*)(ws + (33ull << 20));    //  2 MB  [1024][1024]
  ushort* kkT    = (ushort*)(ws + (35ull << 20));
  ushort* vkT    = (ushort*)(ws + (37ull << 20));
  ushort* kds    = (ushort*)(ws + (39ull << 20));    //  4 MB  [2048][1024]
  ushort* vds    = (ushort*)(ws + (43ull << 20));    //  (contiguous with kds)
  ushort* k_proj = (ushort*)(ws + (79ull << 20));    //  4 MB  [2048][1024]
  ushort* v_projT= (ushort*)(ws + (83ull << 20));    //  4 MB  [32][1024][64]
  ushort* dsm_hi = (ushort*)(ws + (87ull << 20));    // 128 KB [2][64][512]
  ushort* dsm_lo = (ushort*)(ws + (87ull << 20) + (128ull << 10));

  hipFuncSetAttribute((const void*)gemm256_attn,
                      hipFuncAttributeMaxDynamicSharedMemorySize, 131072);

  cvt_split<<<64, 256, 0, stream>>>(kdm, vdm, dsm_hi, dsm_lo);
  // K/V path: ds(512, XCD-grouped) | transpose kkT/vkT(2048)
  pre_kv<<<512 + 2048, 256, 0, stream>>>(
      key, value, kk, vk, dsm_hi, dsm_lo, kkT, vkT, kds, vds);
  // K+V projections + {qkT transpose | query cvt} streaming underneath
  gemm_kv_q<<<256 + 1024 + 2048, 256, 0, stream>>>(
      kds, kkT, vkT, k_proj, v_projT, qk, qkT, query, q_bf);
  // Q projection + attention fused, 16-wave shape
  gemm256_attn<<<256, 1024, 131072, stream>>>(q_bf, qkT, k_proj, v_projT, out);
}

// Round 6
// 127.972 us; speedup vs baseline: 1.1924x; 1.1915x over previous
//
#include <hip/hip_runtime.h>
#include <stdint.h>

// Problem constants
#define B_   32
#define S_   512
#define D_   1024
#define H_   16
#define HD_  64
#define KD_  64
#define NH_  1024   // H*HD

typedef __attribute__((ext_vector_type(8))) short short8;
typedef __attribute__((ext_vector_type(4))) float floatx4;

#define GAS __attribute__((address_space(1)))
#define LAS __attribute__((address_space(3)))

__device__ __forceinline__ ushort f2bf(float f) {
  uint32_t u = __float_as_uint(f);
  u = u + 0x7FFFu + ((u >> 16) & 1u);   // round-to-nearest-even
  return (ushort)(u >> 16);
}

__device__ __forceinline__ float bf2f(ushort h) {
  return __uint_as_float(((uint32_t)h) << 16);
}

__device__ __forceinline__ void gload_lds16(const void* g, void* l) {
  // width=16 global->LDS DMA; LDS dest is wave-uniform base + lane*16
  __builtin_amdgcn_global_load_lds((const GAS uint32_t*)g, (LAS uint32_t*)l, 16, 0, 0);
}

#define BARRIER() asm volatile("s_barrier" ::: "memory")
#define WAITLGKM() asm volatile("s_waitcnt lgkmcnt(0)" ::: "memory")

// ---- split-convert the two downsample mats to hi/lo bf16: [2][64][512] ---
__global__ __launch_bounds__(256) void cvt_split(const float* __restrict__ kdm,
                                                 const float* __restrict__ vdm,
                                                 ushort* __restrict__ hi,
                                                 ushort* __restrict__ lo) {
  int i = blockIdx.x * 256 + threadIdx.x;        // 16384 float4s total
  const float* src = (i < 8192) ? kdm : vdm;
  int j = i & 8191;
  float4 v = ((const float4*)src)[j];
  ushort4 h, l;
  h.x = f2bf(v.x); l.x = f2bf(v.x - bf2f(h.x));
  h.y = f2bf(v.y); l.y = f2bf(v.y - bf2f(h.y));
  h.z = f2bf(v.z); l.z = f2bf(v.z - bf2f(h.z));
  h.w = f2bf(v.w); l.w = f2bf(v.w - bf2f(h.w));
  ((ushort4*)hi)[i] = h;
  ((ushort4*)lo)[i] = l;
}

// ---- R14: pre_kv = {downsample(512) | transpose kkT/vkT(2048)} ----------
__global__ __launch_bounds__(256, 6) void pre_kv(
    const float* __restrict__ key, const float* __restrict__ value,
    const float* __restrict__ kkm, const float* __restrict__ vkm,
    const ushort* __restrict__ dsm_hi, const ushort* __restrict__ dsm_lo,
    ushort* __restrict__ kkT, ushort* __restrict__ vkT,
    ushort* __restrict__ outk, ushort* __restrict__ outv) {
  __shared__ __align__(16) char smem[26624];
  const int blk = blockIdx.x;
  const int tid = threadIdx.x;

  if (blk < 512) {
    // ================= downsample (32-wide s-chunks) ======================
    const int bz = (blk & 7) + ((blk >> 6) << 3);
    const int t  = (blk >> 3) & 7;
    const int z = bz >> 5, b = bz & 31;
    const int c0 = t * 128;
    const float* in = z ? value : key;
    ushort* out     = z ? outv : outk;
    const ushort* Ah = dsm_hi + (size_t)z * (KD_ * S_);
    const ushort* Al = dsm_lo + (size_t)z * (KD_ * S_);

    // lA hi/lo: [64][32] bf16 (4KB each); lB hi/lo: [128][18] uint (9216B each)
    ushort* lAh = (ushort*)smem;                    // 4096 B
    ushort* lAl = (ushort*)(smem + 4096);           // 4096 B
    uint*   lBh = (uint*)(smem + 8192);             // 9216 B
    uint*   lBl = (uint*)(smem + 17408);            // 9216 B  (total 26624)

    const int lane = tid & 63, w = tid >> 6;
    const int lr = lane & 15, lg = lane >> 4;
    const int wn = w * 32;
    const int lam = tid & 31;
    const int d0 = lam * 4;
    const int sp = tid >> 5;          // 0..7

    floatx4 acc[4][2];
#pragma unroll
    for (int m = 0; m < 4; ++m)
#pragma unroll
      for (int n = 0; n < 2; ++n) acc[m][n] = (floatx4){0.f, 0.f, 0.f, 0.f};

    for (int k0 = 0; k0 < S_; k0 += 32) {
      // stage A (dsm) hi/lo: one width-16 DMA per buffer covers [64][32]
      {
        size_t src = (size_t)(tid >> 2) * S_ + k0 + (size_t)(tid & 3) * 8;
        gload_lds16(Ah + src, lAh + w * 512);
        gload_lds16(Al + src, lAl + w * 512);
      }
      // load B tile: 32 s-rows x 128 d-cols, (s, s+1) pairs per thread
      float4 ra[2], rb[2];
#pragma unroll
      for (int si = 0; si < 2; ++si) {
        int s = sp * 2 + si * 16;
        const float* p = in + ((size_t)(b * S_ + k0 + s)) * D_ + c0 + d0;
        ra[si] = *(const float4*)p;
        rb[si] = *(const float4*)(p + D_);
      }
      const int swz = lam & 12;        // XOR on col bits 2-3 keeps b128 contig
#pragma unroll
      for (int si = 0; si < 2; ++si) {
        int col = (sp + si * 8) ^ swz;
        const float* pa = (const float*)&ra[si];
        const float* pb = (const float*)&rb[si];
#pragma unroll
        for (int i = 0; i < 4; ++i) {
          ushort h0 = f2bf(pa[i]);
          ushort l0 = f2bf(pa[i] - bf2f(h0));
          ushort h1 = f2bf(pb[i]);
          ushort l1 = f2bf(pb[i] - bf2f(h1));
          lBh[(d0 + i) * 18 + col] = (uint)h0 | ((uint)h1 << 16);
          lBl[(d0 + i) * 18 + col] = (uint)l0 | ((uint)l1 << 16);
        }
      }
      __syncthreads();
      short8 bh[2], bl[2];
#pragma unroll
      for (int n = 0; n < 2; ++n) {
        int d = wn + n * 16 + lr;
        int off = d * 18 + ((lg * 4) ^ ((d >> 2) & 12));
        bh[n] = *(const short8*)&lBh[off];
        bl[n] = *(const short8*)&lBl[off];
      }
#pragma unroll
      for (int m = 0; m < 4; ++m) {
        int aoff = (m * 16 + lr) * 32 + lg * 8;
        short8 ah = *(const short8*)&lAh[aoff];
        short8 al = *(const short8*)&lAl[aoff];
#pragma unroll
        for (int n = 0; n < 2; ++n) {
          acc[m][n] = __builtin_amdgcn_mfma_f32_16x16x32_bf16(ah, bh[n], acc[m][n], 0, 0, 0);
          acc[m][n] = __builtin_amdgcn_mfma_f32_16x16x32_bf16(ah, bl[n], acc[m][n], 0, 0, 0);
          acc[m][n] = __builtin_amdgcn_mfma_f32_16x16x32_bf16(al, bh[n], acc[m][n], 0, 0, 0);
        }
      }
      __syncthreads();
    }
    size_t obase = (size_t)b * KD_ * D_;
#pragma unroll
    for (int m = 0; m < 4; ++m)
#pragma unroll
      for (int n = 0; n < 2; ++n)
#pragma unroll
        for (int r = 0; r < 4; ++r)
          out[obase + (size_t)(m * 16 + lg * 4 + r) * D_ + c0 + wn + n * 16 + lr] =
              f2bf(acc[m][n][r]);

  } else {
    // ================= transpose+convert kkm/vkm =========================
    const int blk2 = blk - 512;
    const int tz = blk2 >> 10;            // 0: kkm, 1: vkm
    const int rem = blk2 & 1023;
    const int tyb = rem >> 5;
    const int txb = rem & 31;
    const float* in = tz == 0 ? kkm : vkm;
    ushort* outp    = tz == 0 ? kkT : vkT;
    float (*tile)[33] = (float(*)[33])smem;
    const int tx = tid & 31, ty = tid >> 5;
    int x = txb * 32 + tx;
    int y0 = tyb * 32;
#pragma unroll
    for (int j = 0; j < 4; ++j)
      tile[ty + j * 8][tx] = in[(size_t)(y0 + ty + j * 8) * 1024 + x];
    __syncthreads();
    int x2 = tyb * 32 + tx;
    int y2 = txb * 32;
#pragma unroll
    for (int j = 0; j < 4; ++j)
      outp[(size_t)(y2 + ty + j * 8) * 1024 + x2] = f2bf(tile[tx][ty + j * 8]);
  }
}

// ---- K/V projection GEMM fused with {qkT transpose | query cvt} ---------
// R16 (kept): V-half output written TRANSPOSED per batch: vpT[b][1024 hd][64 k]
// (bit-identical values, layout only) so the attention PV step reads V
// fragments coalesced from global and the sV LDS staging disappears.
__global__ __launch_bounds__(256) void gemm_kv_q(
    const ushort* __restrict__ A,     // kds (vds contiguous)
    const ushort* __restrict__ Bt,    // kkT
    const ushort* __restrict__ Bt2,   // vkT
    ushort* __restrict__ C,           // k_proj (normal layout)
    ushort* __restrict__ vpT,         // v_projT [32][1024][64]
    const float* __restrict__ qk, ushort* __restrict__ qkT,
    const float* __restrict__ query, ushort* __restrict__ q_bf) {
  __shared__ __align__(16) char smem[16384];
  const int blk = blockIdx.x;
  const int tid = threadIdx.x;

  if (blk < 256) {
    // ================= 128x128 m97-style GEMM (K/V proj) =================
    ushort* lA = (ushort*)smem;            // [128*32] bf16, 8KB
    ushort* lB = (ushort*)(smem + 8192);   // 8KB
    int xcd = blk & 7, slot = blk >> 3;
    int mt = xcd * 4 + (slot >> 3);        // MT=32
    int nt = slot & 7;
    int m0 = mt * 128, n0 = nt * 128;
    const ushort* Bsel = (mt >= 16) ? Bt2 : Bt;

    int lane = tid & 63, w = tid >> 6;
    int lr = lane & 15, lg = lane >> 4;
    int wm = (w >> 1) * 64, wn = (w & 1) * 64;
    floatx4 acc[4][4];
#pragma unroll
    for (int m = 0; m < 4; ++m)
#pragma unroll
      for (int n = 0; n < 4; ++n) acc[m][n] = (floatx4){0.f, 0.f, 0.f, 0.f};

    for (int k0 = 0; k0 < 1024; k0 += 32) {
#pragma unroll
      for (int i = 0; i < 2; ++i) {
        int c = i * 256 + w * 64 + lane;
        gload_lds16(A + ((size_t)(m0 + (c >> 2)) * 1024 + k0 + (c & 3) * 8),
                    &lA[(i * 256 + w * 64) * 8]);
        gload_lds16(Bsel + ((size_t)(n0 + (c >> 2)) * 1024 + k0 + (c & 3) * 8),
                    &lB[(i * 256 + w * 64) * 8]);
      }
      __syncthreads();
      short8 af[4], bfr[4];
#pragma unroll
      for (int m = 0; m < 4; ++m)
        af[m] = *(const short8*)&lA[(wm + m * 16 + lr) * 32 + lg * 8];
#pragma unroll
      for (int n = 0; n < 4; ++n)
        bfr[n] = *(const short8*)&lB[(wn + n * 16 + lr) * 32 + lg * 8];
#pragma unroll
      for (int m = 0; m < 4; ++m)
#pragma unroll
        for (int n = 0; n < 4; ++n)
          acc[m][n] = __builtin_amdgcn_mfma_f32_16x16x32_bf16(af[m], bfr[n], acc[m][n], 0, 0, 0);
      __syncthreads();
    }
    if (mt < 16) {
      // K half: normal [b*64+k][1024] layout
#pragma unroll
      for (int m = 0; m < 4; ++m)
#pragma unroll
        for (int n = 0; n < 4; ++n)
#pragma unroll
          for (int r = 0; r < 4; ++r)
            C[(size_t)(m0 + wm + m * 16 + lg * 4 + r) * 1024 + n0 + wn + n * 16 + lr] =
                f2bf(acc[m][n][r]);
    } else {
      // V half: transposed vpT[b][hd][k]; r-consecutive = k-consecutive
#pragma unroll
      for (int m = 0; m < 4; ++m)
#pragma unroll
        for (int n = 0; n < 4; ++n) {
          int rowV = m0 - 2048 + wm + m * 16 + lg * 4;
          int b = rowV >> 6, k = rowV & 63;
          int hd = n0 + wn + n * 16 + lr;
          ushort4 o;
          o.x = f2bf(acc[m][n][0]); o.y = f2bf(acc[m][n][1]);
          o.z = f2bf(acc[m][n][2]); o.w = f2bf(acc[m][n][3]);
          *(ushort4*)&vpT[(size_t)b * 65536 + (size_t)hd * 64 + k] = o;
        }
    }

  } else if (blk < 256 + 1024) {
    // ================= transpose+convert qk -> qkT =======================
    const int blk2 = blk - 256;
    const int tyb = blk2 >> 5;
    const int txb = blk2 & 31;
    float (*tile)[33] = (float(*)[33])smem;
    const int tx = tid & 31, ty = tid >> 5;
    int x = txb * 32 + tx;
    int y0 = tyb * 32;
#pragma unroll
    for (int j = 0; j < 4; ++j)
      tile[ty + j * 8][tx] = qk[(size_t)(y0 + ty + j * 8) * 1024 + x];
    __syncthreads();
    int x2 = tyb * 32 + tx;
    int y2 = txb * 32;
#pragma unroll
    for (int j = 0; j < 4; ++j)
      qkT[(size_t)(y2 + ty + j * 8) * 1024 + x2] = f2bf(tile[tx][ty + j * 8]);

  } else {
    // ================= fp32 -> bf16 convert (query), coarsened ============
    const size_t base = (size_t)(blk - 1280) * 2048 + tid;
#pragma unroll
    for (int j = 0; j < 8; ++j) {
      size_t i = base + (size_t)j * 256;
      float4 v = ((const float4*)query)[i];
      ushort4 o;
      o.x = f2bf(v.x); o.y = f2bf(v.y); o.z = f2bf(v.z); o.w = f2bf(v.w);
      ((ushort4*)q_bf)[i] = o;
    }
  }
}

// ---- fused Q-projection (256x256 8-phase) + attention epilogue ----------
// R18: REVERT to the R2-proven 512-thread/8-wave kernel (55.8us, VGPR 124,
// no spill). The 1024-thread reshape (R16/R17) could not get a >=128-VGPR
// budget from the compiler (VGPR pinned at 64 both rounds, 66MB spill
// stream) — abandoned. Single change vs R2: the sV LDS staging block is
// DELETED; PV reads V directly from global vpT[b][hd][k] (same addresses
// the sV path produced, L2-hot, b128-coalesced; address math proven in
// R4/R5). Saves 16K scalar loads + 16K LDS writes + a block syncthreads.
__global__ __launch_bounds__(512, 2) void gemm256_attn(
    const ushort* __restrict__ A, const ushort* __restrict__ Bt,
    const ushort* __restrict__ kp, const ushort* __restrict__ vpT,
    float* __restrict__ out) {
  extern __shared__ ushort lds[];
  ushort* ldsA = lds;                   // [2][256*64]
  ushort* ldsB = lds + 2 * 256 * 64;    // [2][256*64]
  const int tid = threadIdx.x;
  const int w = tid >> 6, lane = tid & 63;
  const int lr = lane & 15, lg = lane >> 4;
  const int wm = w >> 2, wn = w & 3;    // 2 x 4 waves
  const int bid = blockIdx.x;
  const int mt = (bid & 7) * 8 + ((bid >> 3) >> 2);   // 0..63
  const int nt = (bid >> 3) & 3;
  const int m0 = mt * 256, n0 = nt * 256;
  const int NT = 16;                    // K=1024 / 64

  const int srow = tid >> 3;
  const int sslot = tid & 7;

  auto stageA = [&](int sl, int ch, int k0) {
    int rloc = ch * 64 + srow;
    int gs = sslot ^ (rloc & 7);
    gload_lds16(A + (size_t)(m0 + rloc) * 1024 + k0 + gs * 8,
                ldsA + sl * (256 * 64) + ch * (64 * 64) + w * 512);
  };
  auto stageB = [&](int sl, int ch, int k0) {
    int rloc = ch * 64 + srow;
    int gs = sslot ^ (rloc & 7);
    gload_lds16(Bt + (size_t)(n0 + rloc) * 1024 + k0 + gs * 8,
                ldsB + sl * (256 * 64) + ch * (64 * 64) + w * 512);
  };

  short8 af[4][2], bf[2][2];
  auto loadA = [&](int sl, int mh) {
#pragma unroll
    for (int i = 0; i < 4; ++i) {
      int row = wm * 128 + (mh * 4 + i) * 16 + lr;
#pragma unroll
      for (int kk = 0; kk < 2; ++kk) {
        int col = (((kk * 4 + lg) ^ (row & 7)) * 8);
        af[i][kk] = *(const short8*)&ldsA[sl * (256 * 64) + row * 64 + col];
      }
    }
  };
  auto loadB = [&](int sl, int nh) {
#pragma unroll
    for (int j = 0; j < 2; ++j) {
      int row = wn * 64 + (nh * 2 + j) * 16 + lr;
#pragma unroll
      for (int kk = 0; kk < 2; ++kk) {
        int col = (((kk * 4 + lg) ^ (row & 7)) * 8);
        bf[j][kk] = *(const short8*)&ldsB[sl * (256 * 64) + row * 64 + col];
      }
    }
  };

  floatx4 acc[8][4];
#pragma unroll
  for (int i = 0; i < 8; ++i)
#pragma unroll
    for (int j = 0; j < 4; ++j) acc[i][j] = (floatx4){0.f, 0.f, 0.f, 0.f};

  auto mma16 = [&](int mh, int nh) {
    __builtin_amdgcn_s_setprio(1);
#pragma unroll
    for (int i = 0; i < 4; ++i)
#pragma unroll
      for (int j = 0; j < 2; ++j)
#pragma unroll
        for (int kk = 0; kk < 2; ++kk)
          acc[mh * 4 + i][nh * 2 + j] = __builtin_amdgcn_mfma_f32_16x16x32_bf16(
              af[i][kk], bf[j][kk], acc[mh * 4 + i][nh * 2 + j], 0, 0, 0);
    __builtin_amdgcn_s_setprio(0);
  };

#pragma unroll
  for (int ch = 0; ch < 4; ++ch) { stageA(0, ch, 0); stageB(0, ch, 0); }

#pragma unroll 2
  for (int t = 0; t < NT; ++t) {
    const int s = t & 1, ns = s ^ 1;
    const int kn = (t + 1) << 6;
    const bool more = (t + 1 < NT);
    if (more) { stageA(ns, 0, kn); stageA(ns, 1, kn); }
    if (more) { asm volatile("s_waitcnt vmcnt(2)" ::: "memory"); }
    else      { asm volatile("s_waitcnt vmcnt(0)" ::: "memory"); }
    BARRIER();
    loadA(s, 0); loadB(s, 0);
    WAITLGKM();
    mma16(0, 0);
    BARRIER();
    loadB(s, 1);
    if (more) { stageB(ns, 0, kn); stageB(ns, 1, kn); }
    BARRIER();
    WAITLGKM();
    mma16(0, 1);
    BARRIER();
    loadA(s, 1);
    if (more) { stageA(ns, 2, kn); stageA(ns, 3, kn); }
    BARRIER();
    WAITLGKM();
    mma16(1, 1);
    BARRIER();
    loadB(s, 0);
    if (more) { stageB(ns, 2, kn); stageB(ns, 3, kn); }
    BARRIER();
    WAITLGKM();
    mma16(1, 0);
    BARRIER();
  }
  // After the final BARRIER all LDS activity is drained: buffers reusable.

  // ================= attention tail (no q_proj round-trip) =================
  // LDS overlay: per-wave Q/P region [64][72] (8 x 9KB = 72KB). V is read
  // directly from global vpT (R18) — no sV staging, no block syncthreads.
  ushort* QP = lds + w * 4608;          // this wave's Q/P region
  const int b = mt >> 1;
  const int hq = nt * 4 + wn;           // this wave's head

#pragma unroll
  for (int half = 0; half < 2; ++half) {
    const int srow0 = (mt & 1) * 256 + wm * 128 + half * 64;  // s-base of unit
    // ---- write this half's Q tile (from acc, constant indices) ----
#pragma unroll
    for (int mi = 0; mi < 4; ++mi)
#pragma unroll
      for (int nj = 0; nj < 4; ++nj)
#pragma unroll
        for (int r = 0; r < 4; ++r)
          QP[(mi * 16 + lg * 4 + r) * 72 + nj * 16 + lr] =
              f2bf(acc[half * 4 + mi][nj][r]);
    WAITLGKM();
    __builtin_amdgcn_sched_barrier(0);
    // ---- QK^T: Q from LDS region, K from global (L2-hot, 8KB/head) ----
    floatx4 qacc[4][4];
#pragma unroll
    for (int m = 0; m < 4; ++m)
#pragma unroll
      for (int n = 0; n < 4; ++n) qacc[m][n] = (floatx4){0.f, 0.f, 0.f, 0.f};
#pragma unroll
    for (int kk = 0; kk < 2; ++kk) {
      short8 qa[4], kb[4];
#pragma unroll
      for (int m = 0; m < 4; ++m)
        qa[m] = *(const short8*)&QP[(m * 16 + lr) * 72 + kk * 32 + lg * 8];
#pragma unroll
      for (int n = 0; n < 4; ++n)
        kb[n] = *(const short8*)(kp + ((size_t)b * KD_ + n * 16 + lr) * 1024 +
                                 hq * HD_ + kk * 32 + lg * 8);
#pragma unroll
      for (int m = 0; m < 4; ++m)
#pragma unroll
        for (int n = 0; n < 4; ++n)
          qacc[m][n] = __builtin_amdgcn_mfma_f32_16x16x32_bf16(qa[m], kb[n], qacc[m][n], 0, 0, 0);
    }
    // ---- mask + softmax (verbatim) ----
#pragma unroll
    for (int m = 0; m < 4; ++m) {
#pragma unroll
      for (int r = 0; r < 4; ++r) {
        int srow2 = srow0 + m * 16 + lg * 4 + r;
        float vals[4];
        float mx = -1e30f;
#pragma unroll
        for (int n = 0; n < 4; ++n) {
          int col = n * 16 + lr;
          float val = qacc[m][n][r];
          val = (col <= srow2) ? val : -1e30f;
          vals[n] = val;
          mx = fmaxf(mx, val);
        }
        mx = fmaxf(mx, __shfl_xor(mx, 1));
        mx = fmaxf(mx, __shfl_xor(mx, 2));
        mx = fmaxf(mx, __shfl_xor(mx, 4));
        mx = fmaxf(mx, __shfl_xor(mx, 8));
        float sum = 0.f;
#pragma unroll
        for (int n = 0; n < 4; ++n) {
          float e = __expf(vals[n] - mx);
          vals[n] = e;
          sum += e;
        }
        sum += __shfl_xor(sum, 1);
        sum += __shfl_xor(sum, 2);
        sum += __shfl_xor(sum, 4);
        sum += __shfl_xor(sum, 8);
        float inv = 1.0f / sum;
#pragma unroll
        for (int n = 0; n < 4; ++n)
          QP[(m * 16 + lg * 4 + r) * 72 + n * 16 + lr] = f2bf(vals[n] * inv);
      }
    }
    WAITLGKM();
    __builtin_amdgcn_sched_barrier(0);
    // ---- PV: P from LDS, V direct from global vpT[b][hd][k] ----
    floatx4 oacc[4][4];
#pragma unroll
    for (int m = 0; m < 4; ++m)
#pragma unroll
      for (int n = 0; n < 4; ++n) oacc[m][n] = (floatx4){0.f, 0.f, 0.f, 0.f};
#pragma unroll
    for (int kk = 0; kk < 2; ++kk) {
      short8 pa[4], vb[4];
#pragma unroll
      for (int m = 0; m < 4; ++m)
        pa[m] = *(const short8*)&QP[(m * 16 + lr) * 72 + kk * 32 + lg * 8];
#pragma unroll
      for (int n = 0; n < 4; ++n)
        vb[n] = *(const short8*)(vpT + (size_t)b * 65536 +
                                 (size_t)(hq * HD_ + n * 16 + lr) * 64 +
                                 kk * 32 + lg * 8);
#pragma unroll
      for (int m = 0; m < 4; ++m)
#pragma unroll
        for (int n = 0; n < 4; ++n)
          oacc[m][n] = __builtin_amdgcn_mfma_f32_16x16x32_bf16(pa[m], vb[n], oacc[m][n], 0, 0, 0);
    }
#pragma unroll
    for (int m = 0; m < 4; ++m)
#pragma unroll
      for (int n = 0; n < 4; ++n)
#pragma unroll
        for (int r = 0; r < 4; ++r)
          out[((size_t)b * S_ + srow0 + m * 16 + lg * 4 + r) * 1024 +
              hq * HD_ + n * 16 + lr] = oacc[m][n][r];
  }
}

// ------------------------------- launcher ---------------------------------
extern "C" void kernel_launch(void* const* d_in, const int* in_sizes, int n_in,
                              void* d_out, int out_size, void* d_ws, size_t ws_size,
                              hipStream_t stream) {
  const float* query = (const float*)d_in[0];
  const float* key   = (const float*)d_in[1];
  const float* value = (const float*)d_in[2];
  const float* qk    = (const float*)d_in[3];
  const float* kk    = (const float*)d_in[4];
  const float* vk    = (const float*)d_in[5];
  const float* kdm   = (const float*)d_in[6];
  const float* vdm   = (const float*)d_in[7];
  float* out = (float*)d_out;

  char* ws = (char*)d_ws;
  if (ws_size < (90ull << 20)) return;
  ushort* q_bf   = (ushort*)(ws);                    // 32 MB  [16384][1024]
  ushort* qkT    = (ushort*)(ws + (33ull << 20));    //  2 MB  [1024][1024]
  ushort* kkT    = (ushort*)(ws + (35ull << 20));
  ushort* vkT    = (ushort*)(ws + (37ull << 20));
  ushort* kds    = (ushort*)(ws + (39ull << 20));    //  4 MB  [2048][1024]
  ushort* vds    = (ushort*)(ws + (43ull << 20));    //  (contiguous with kds)
  ushort* k_proj = (ushort*)(ws + (79ull << 20));    //  4 MB  [2048][1024]
  ushort* v_projT= (ushort*)(ws + (83ull << 20));    //  4 MB  [32][1024][64]
  ushort* dsm_hi = (ushort*)(ws + (87ull << 20));    // 128 KB [2][64][512]
  ushort* dsm_lo = (ushort*)(ws + (87ull << 20) + (128ull << 10));

  hipFuncSetAttribute((const void*)gemm256_attn,
                      hipFuncAttributeMaxDynamicSharedMemorySize, 131072);

  cvt_split<<<64, 256, 0, stream>>>(kdm, vdm, dsm_hi, dsm_lo);
  // K/V path: ds(512, XCD-grouped) | transpose kkT/vkT(2048)
  pre_kv<<<512 + 2048, 256, 0, stream>>>(
      key, value, kk, vk, dsm_hi, dsm_lo, kkT, vkT, kds, vds);
  // K+V projections + {qkT transpose | query cvt} streaming underneath
  gemm_kv_q<<<256 + 1024 + 2048, 256, 0, stream>>>(
      kds, kkT, vkT, k_proj, v_projT, qk, qkT, query, q_bf);
  // Q projection + attention fused (q_proj never materialized)
  gemm256_attn<<<256, 512, 131072, stream>>>(q_bf, qkT, k_proj, v_projT, out);
}